// Round 1
// baseline (1650.038 us; speedup 1.0000x reference)
//
#include <hip/hip_runtime.h>
#include <math.h>

// Softplus (stable) + sigmoid in one shot.
// sp(z) = max(z,0) + log1p(exp(-|z|)),  sig(z) = z>=0 ? 1/(1+e) : e/(1+e) = 1 - 1/(1+e)
__device__ __forceinline__ void sp_sig(float z, float& h, float& s) {
    float az = fabsf(z);
    float e  = __expf(-az);
    float l  = log1pf(e);
    h = fmaxf(z, 0.0f) + l;
    float r = __fdividef(1.0f, 1.0f + e);
    s = (z >= 0.0f) ? r : (1.0f - r);
}

__global__ __launch_bounds__(256) void energy_kernel(
    const float* __restrict__ Fg,
    const float* __restrict__ W0, const float* __restrict__ b0,
    const float* __restrict__ W1, const float* __restrict__ b1,
    const float* __restrict__ W2, const float* __restrict__ b2,
    float* __restrict__ P, float* __restrict__ Wv, int n)
{
    int idx = blockIdx.x * blockDim.x + threadIdx.x;
    if (idx >= n) return;

    const float* f = Fg + (size_t)idx * 9;
    float f00=f[0], f01=f[1], f02=f[2];
    float f10=f[3], f11=f[4], f12=f[5];
    float f20=f[6], f21=f[7], f22=f[8];

    // C = F^T F (symmetric)
    float c00 = f00*f00 + f10*f10 + f20*f20;
    float c01 = f00*f01 + f10*f11 + f20*f21;
    float c02 = f00*f02 + f10*f12 + f20*f22;
    float c11 = f01*f01 + f11*f11 + f21*f21;
    float c12 = f01*f02 + f11*f12 + f21*f22;
    float c22 = f02*f02 + f12*f12 + f22*f22;

    // cof(F) = dJ/dF
    float cf00 = f11*f22 - f12*f21;
    float cf01 = f12*f20 - f10*f22;
    float cf02 = f10*f21 - f11*f20;
    float cf10 = f02*f21 - f01*f22;
    float cf11 = f00*f22 - f02*f20;
    float cf12 = f01*f20 - f00*f21;
    float cf20 = f01*f12 - f02*f11;
    float cf21 = f02*f10 - f00*f12;
    float cf22 = f00*f11 - f01*f10;
    float J = f00*cf00 + f01*cf01 + f02*cf02;

    // A = adj(C) = cof(C) (symmetric): equals det(C) * inv(C)
    float A00 = c11*c22 - c12*c12;
    float A01 = c02*c12 - c01*c22;
    float A02 = c01*c12 - c02*c11;
    float A11 = c00*c22 - c02*c02;
    float A12 = c01*c02 - c00*c12;
    float A22 = c00*c11 - c01*c01;

    float I1  = c00 + c11 + c22;
    float I2  = A00 + A11 + A22;
    float I7  = c00*c00 + c11*c11 + c22*c22;
    float I11v= A00*A00 + A11*A11 + A22*A22;

    float iv[6];
    iv[0] = I1; iv[1] = I2; iv[2] = J; iv[3] = -J; iv[4] = I7; iv[5] = I11v;

    // ---------------- MLP forward ----------------
    float z0[32];
    #pragma unroll
    for (int j = 0; j < 32; ++j) z0[j] = b0[j];
    #pragma unroll
    for (int m = 0; m < 6; ++m) {
        float x = iv[m];
        #pragma unroll
        for (int j = 0; j < 32; ++j) z0[j] = fmaf(x, W0[m*32 + j], z0[j]);
    }
    float h0[32], s0[32];
    #pragma unroll
    for (int j = 0; j < 32; ++j) sp_sig(z0[j], h0[j], s0[j]);

    float z1[32];
    #pragma unroll
    for (int j = 0; j < 32; ++j) z1[j] = b1[j];
    #pragma unroll
    for (int k = 0; k < 32; ++k) {
        float hk = h0[k];
        #pragma unroll
        for (int j = 0; j < 32; ++j) z1[j] = fmaf(hk, W1[k*32 + j], z1[j]);
    }

    // output + g1 = dout/dz1 = W2 * sigmoid(z1)
    float g1[32];
    float o[4] = {0.f, 0.f, 0.f, 0.f};
    #pragma unroll
    for (int j = 0; j < 32; ++j) {
        float h1, s1;
        sp_sig(z1[j], h1, s1);
        float w2 = W2[j];
        o[j & 3] = fmaf(h1, w2, o[j & 3]);
        g1[j] = w2 * s1;
    }
    float outv = (o[0] + o[1]) + (o[2] + o[3]) + b2[0];

    // ---------------- MLP backward ----------------
    // d[m] = dout/d iv[m]
    float d0=0.f, d1=0.f, d2=0.f, d3=0.f, d4=0.f, d5=0.f;
    #pragma unroll
    for (int k = 0; k < 32; ++k) {
        float p0=0.f, p1=0.f, p2=0.f, p3=0.f;
        #pragma unroll
        for (int j = 0; j < 32; j += 4) {
            p0 = fmaf(W1[k*32 + j + 0], g1[j + 0], p0);
            p1 = fmaf(W1[k*32 + j + 1], g1[j + 1], p1);
            p2 = fmaf(W1[k*32 + j + 2], g1[j + 2], p2);
            p3 = fmaf(W1[k*32 + j + 3], g1[j + 3], p3);
        }
        float g0k = ((p0 + p1) + (p2 + p3)) * s0[k];
        d0 = fmaf(W0[0*32 + k], g0k, d0);
        d1 = fmaf(W0[1*32 + k], g0k, d1);
        d2 = fmaf(W0[2*32 + k], g0k, d2);
        d3 = fmaf(W0[3*32 + k], g0k, d3);
        d4 = fmaf(W0[4*32 + k], g0k, d4);
        d5 = fmaf(W0[5*32 + k], g0k, d5);
    }

    // ---------------- Assemble P = F*M + aJ*cof(F) ----------------
    // M = 2 d0 I + 2 d1 (I1 I - C) + 4 d4 diag(C) + 2 d5 G11   (symmetric)
    // G11 = (2/detC) * (I11 * A - A diag(A00,A11,A22) A),  detC = J^2
    float detC = J * J;
    float inv2 = __fdividef(2.0f, detC);

    float w0 = A00, w1 = A11, w2d = A22;
    float T00 = w0*A00*A00 + w1*A01*A01 + w2d*A02*A02;
    float T01 = w0*A00*A01 + w1*A01*A11 + w2d*A02*A12;
    float T02 = w0*A00*A02 + w1*A01*A12 + w2d*A02*A22;
    float T11 = w0*A01*A01 + w1*A11*A11 + w2d*A12*A12;
    float T12 = w0*A01*A02 + w1*A11*A12 + w2d*A12*A22;
    float T22 = w0*A02*A02 + w1*A12*A12 + w2d*A22*A22;

    float G00 = inv2 * (I11v*A00 - T00);
    float G01 = inv2 * (I11v*A01 - T01);
    float G02 = inv2 * (I11v*A02 - T02);
    float G11e= inv2 * (I11v*A11 - T11);
    float G12 = inv2 * (I11v*A12 - T12);
    float G22 = inv2 * (I11v*A22 - T22);

    float aJ  = d2 - d3;
    float t1  = 2.0f * d0;
    float t2  = 2.0f * d1;
    float t7  = 4.0f * d4;
    float t11 = 2.0f * d5;

    float m00 = t1 + t2*(I1 - c00) + t7*c00 + t11*G00;
    float m01 =      -t2*c01               + t11*G01;
    float m02 =      -t2*c02               + t11*G02;
    float m11 = t1 + t2*(I1 - c11) + t7*c11 + t11*G11e;
    float m12 =      -t2*c12               + t11*G12;
    float m22 = t1 + t2*(I1 - c22) + t7*c22 + t11*G22;

    float* p = P + (size_t)idx * 9;
    p[0] = f00*m00 + f01*m01 + f02*m02 + aJ*cf00;
    p[1] = f00*m01 + f01*m11 + f02*m12 + aJ*cf01;
    p[2] = f00*m02 + f01*m12 + f02*m22 + aJ*cf02;
    p[3] = f10*m00 + f11*m01 + f12*m02 + aJ*cf10;
    p[4] = f10*m01 + f11*m11 + f12*m12 + aJ*cf11;
    p[5] = f10*m02 + f11*m12 + f12*m22 + aJ*cf12;
    p[6] = f20*m00 + f21*m01 + f22*m02 + aJ*cf20;
    p[7] = f20*m01 + f21*m11 + f22*m12 + aJ*cf21;
    p[8] = f20*m02 + f21*m12 + f22*m22 + aJ*cf22;

    Wv[idx] = outv;
}

extern "C" void kernel_launch(void* const* d_in, const int* in_sizes, int n_in,
                              void* d_out, int out_size, void* d_ws, size_t ws_size,
                              hipStream_t stream) {
    const float* F  = (const float*)d_in[0];
    const float* W0 = (const float*)d_in[1];
    const float* b0 = (const float*)d_in[2];
    const float* W1 = (const float*)d_in[3];
    const float* b1 = (const float*)d_in[4];
    const float* W2 = (const float*)d_in[5];
    const float* b2 = (const float*)d_in[6];
    int n = in_sizes[0] / 9;
    float* out = (float*)d_out;
    float* P  = out;                       // [n,3,3] flat
    float* Wv = out + (size_t)n * 9;       // [n,1] flat

    int block = 256;
    int grid = (n + block - 1) / block;
    hipLaunchKernelGGL(energy_kernel, dim3(grid), dim3(block), 0, stream,
                       F, W0, b0, W1, b1, W2, b2, P, Wv, n);
}

// Round 2
// 1528.436 us; speedup vs baseline: 1.0796x; 1.0796x over previous
//
#include <hip/hip_runtime.h>
#include <math.h>

__device__ __forceinline__ float fast_rcp(float x) { return __builtin_amdgcn_rcpf(x); }

// Softplus + sigmoid using only HW instructions (v_exp_f32 / v_log_f32 / v_rcp_f32).
// sp(z) = max(z,0) + log(1 + exp(-|z|)); 1+e in (1,2] so v_log is accurate and
// for tiny e the absolute error is < 1e-7 (irrelevant at 2% threshold).
__device__ __forceinline__ void sp_sig(float z, float& h, float& s) {
    float az = fabsf(z);
    float e  = __expf(-az);              // v_exp_f32 path
    float r  = fast_rcp(1.0f + e);       // 1/(1+e), ~1 ulp
    h = fmaxf(z, 0.0f) + __logf(1.0f + e);
    s = (z >= 0.0f) ? r : (1.0f - r);
}

__global__ __launch_bounds__(256, 4) void energy_kernel(
    const float* __restrict__ Fg,
    const float* __restrict__ W0, const float* __restrict__ b0,
    const float* __restrict__ W1, const float* __restrict__ b1,
    const float* __restrict__ W2, const float* __restrict__ b2,
    float* __restrict__ P, float* __restrict__ Wv, int n)
{
    // ---- stage all weights in LDS (5.3 KB); all lanes read the same address
    // ---- afterwards -> broadcast, conflict-free, immediate-offset ds_reads.
    __shared__ float lw[1344];
    const int tid = threadIdx.x;
    #pragma unroll
    for (int i = 0; i < 192; i += 256) { int t = i + tid; if (t < 192) lw[t] = W0[t]; }
    if (tid < 32) lw[192 + tid] = b0[tid];
    #pragma unroll
    for (int i = 0; i < 1024; i += 256) lw[224 + i + tid] = W1[i + tid];
    if (tid < 32) lw[1248 + tid] = b1[tid];
    if (tid < 32) lw[1280 + tid] = W2[tid];
    if (tid == 0) lw[1312] = b2[0];
    __syncthreads();

    int idx = blockIdx.x * blockDim.x + tid;
    if (idx >= n) return;

    const float* f = Fg + (size_t)idx * 9;
    float f00=f[0], f01=f[1], f02=f[2];
    float f10=f[3], f11=f[4], f12=f[5];
    float f20=f[6], f21=f[7], f22=f[8];

    // ---- invariants (C, adj(C) used only here; recomputed for the epilogue) ----
    float iv0, iv1, iv2, iv4, iv5;  // I1, I2, J, I7, I11
    {
        float c00 = f00*f00 + f10*f10 + f20*f20;
        float c01 = f00*f01 + f10*f11 + f20*f21;
        float c02 = f00*f02 + f10*f12 + f20*f22;
        float c11 = f01*f01 + f11*f11 + f21*f21;
        float c12 = f01*f02 + f11*f12 + f21*f22;
        float c22 = f02*f02 + f12*f12 + f22*f22;

        float A00 = c11*c22 - c12*c12;
        float A01 = c02*c12 - c01*c22;
        float A02 = c01*c12 - c02*c11;
        float A11 = c00*c22 - c02*c02;
        float A12 = c01*c02 - c00*c12;
        float A22 = c00*c11 - c01*c01;

        iv0 = c00 + c11 + c22;
        iv1 = A00 + A11 + A22;
        iv2 = f00*(f11*f22 - f12*f21) - f01*(f10*f22 - f12*f20) + f02*(f10*f21 - f11*f20);
        iv4 = c00*c00 + c11*c11 + c22*c22;
        iv5 = A00*A00 + A11*A11 + A22*A22;
    }

    // ---------------- MLP forward ----------------
    float h0[32], s0[32];
    {
        float z0[32];
        #pragma unroll
        for (int j = 0; j < 32; ++j) z0[j] = lw[192 + j];
        #pragma unroll
        for (int j = 0; j < 32; ++j) {
            float z = z0[j];
            z = fmaf(iv0, lw[0*32 + j], z);
            z = fmaf(iv1, lw[1*32 + j], z);
            z = fmaf(iv2, lw[2*32 + j], z);
            z = fmaf(-iv2, lw[3*32 + j], z);
            z = fmaf(iv4, lw[4*32 + j], z);
            z = fmaf(iv5, lw[5*32 + j], z);
            sp_sig(z, h0[j], s0[j]);
        }
    }

    float g1[32];   // z1 -> g1 in place
    {
        float z1[32];
        #pragma unroll
        for (int j = 0; j < 32; ++j) z1[j] = lw[1248 + j];
        #pragma unroll
        for (int k = 0; k < 32; ++k) {
            float hk = h0[k];
            #pragma unroll
            for (int j = 0; j < 32; ++j) z1[j] = fmaf(hk, lw[224 + k*32 + j], z1[j]);
        }
        float o0=0.f, o1=0.f, o2=0.f, o3=0.f;
        #pragma unroll
        for (int j = 0; j < 32; ++j) {
            float h1, s1;
            sp_sig(z1[j], h1, s1);
            float w2 = lw[1280 + j];
            if ((j & 3) == 0) o0 = fmaf(h1, w2, o0);
            else if ((j & 3) == 1) o1 = fmaf(h1, w2, o1);
            else if ((j & 3) == 2) o2 = fmaf(h1, w2, o2);
            else o3 = fmaf(h1, w2, o3);
            g1[j] = w2 * s1;
        }
        Wv[idx] = (o0 + o1) + (o2 + o3) + lw[1312];
    }

    // ---------------- MLP backward: d[m] = dOut/d iv[m] ----------------
    float d0=0.f, d1=0.f, d2=0.f, d3=0.f, d4=0.f, d5=0.f;
    #pragma unroll
    for (int k = 0; k < 32; ++k) {
        float p0=0.f, p1=0.f, p2=0.f, p3=0.f;
        #pragma unroll
        for (int j = 0; j < 32; j += 4) {
            p0 = fmaf(lw[224 + k*32 + j + 0], g1[j + 0], p0);
            p1 = fmaf(lw[224 + k*32 + j + 1], g1[j + 1], p1);
            p2 = fmaf(lw[224 + k*32 + j + 2], g1[j + 2], p2);
            p3 = fmaf(lw[224 + k*32 + j + 3], g1[j + 3], p3);
        }
        float g0k = ((p0 + p1) + (p2 + p3)) * s0[k];
        d0 = fmaf(lw[0*32 + k], g0k, d0);
        d1 = fmaf(lw[1*32 + k], g0k, d1);
        d2 = fmaf(lw[2*32 + k], g0k, d2);
        d3 = fmaf(lw[3*32 + k], g0k, d3);
        d4 = fmaf(lw[4*32 + k], g0k, d4);
        d5 = fmaf(lw[5*32 + k], g0k, d5);
    }

    // Block CSE with the prologue so C/adj(C)/cof(F) are REcomputed here
    // (keeps the MLP-phase live set ~115 VGPRs -> 4 waves/SIMD).
    asm volatile("" : "+v"(f00), "+v"(f01), "+v"(f02),
                      "+v"(f10), "+v"(f11), "+v"(f12),
                      "+v"(f20), "+v"(f21), "+v"(f22));

    // ---------------- epilogue: P = F*M + (d2-d3)*cof(F) ----------------
    float c00 = f00*f00 + f10*f10 + f20*f20;
    float c01 = f00*f01 + f10*f11 + f20*f21;
    float c02 = f00*f02 + f10*f12 + f20*f22;
    float c11 = f01*f01 + f11*f11 + f21*f21;
    float c12 = f01*f02 + f11*f12 + f21*f22;
    float c22 = f02*f02 + f12*f12 + f22*f22;

    float A00 = c11*c22 - c12*c12;
    float A01 = c02*c12 - c01*c22;
    float A02 = c01*c12 - c02*c11;
    float A11 = c00*c22 - c02*c02;
    float A12 = c01*c02 - c00*c12;
    float A22 = c00*c11 - c01*c01;

    float cf00 = f11*f22 - f12*f21;
    float cf01 = f12*f20 - f10*f22;
    float cf02 = f10*f21 - f11*f20;
    float cf10 = f02*f21 - f01*f22;
    float cf11 = f00*f22 - f02*f20;
    float cf12 = f01*f20 - f00*f21;
    float cf20 = f01*f12 - f02*f11;
    float cf21 = f02*f10 - f00*f12;
    float cf22 = f00*f11 - f01*f10;
    float J  = f00*cf00 + f01*cf01 + f02*cf02;
    float I1 = c00 + c11 + c22;
    float I11v = A00*A00 + A11*A11 + A22*A22;

    // G11 = (2/detC) * (I11*A - A diag(A00,A11,A22) A), detC = J^2
    float inv2 = 2.0f * fast_rcp(J * J);

    float T00 = A00*A00*A00 + A11*A01*A01 + A22*A02*A02;
    float T01 = A00*A00*A01 + A11*A01*A11 + A22*A02*A12;
    float T02 = A00*A00*A02 + A11*A01*A12 + A22*A02*A22;
    float T11 = A00*A01*A01 + A11*A11*A11 + A22*A12*A12;
    float T12 = A00*A01*A02 + A11*A11*A12 + A22*A12*A22;
    float T22 = A00*A02*A02 + A11*A12*A12 + A22*A22*A22;

    float G00 = inv2 * (I11v*A00 - T00);
    float G01 = inv2 * (I11v*A01 - T01);
    float G02 = inv2 * (I11v*A02 - T02);
    float G11e= inv2 * (I11v*A11 - T11);
    float G12 = inv2 * (I11v*A12 - T12);
    float G22 = inv2 * (I11v*A22 - T22);

    float aJ  = d2 - d3;
    float t1  = 2.0f * d0;
    float t2  = 2.0f * d1;
    float t7  = 4.0f * d4;
    float t11 = 2.0f * d5;

    float m00 = t1 + t2*(I1 - c00) + t7*c00 + t11*G00;
    float m01 =      -t2*c01               + t11*G01;
    float m02 =      -t2*c02               + t11*G02;
    float m11 = t1 + t2*(I1 - c11) + t7*c11 + t11*G11e;
    float m12 =      -t2*c12               + t11*G12;
    float m22 = t1 + t2*(I1 - c22) + t7*c22 + t11*G22;

    float* p = P + (size_t)idx * 9;
    p[0] = f00*m00 + f01*m01 + f02*m02 + aJ*cf00;
    p[1] = f00*m01 + f01*m11 + f02*m12 + aJ*cf01;
    p[2] = f00*m02 + f01*m12 + f02*m22 + aJ*cf02;
    p[3] = f10*m00 + f11*m01 + f12*m02 + aJ*cf10;
    p[4] = f10*m01 + f11*m11 + f12*m12 + aJ*cf11;
    p[5] = f10*m02 + f11*m12 + f12*m22 + aJ*cf12;
    p[6] = f20*m00 + f21*m01 + f22*m02 + aJ*cf20;
    p[7] = f20*m01 + f21*m11 + f22*m12 + aJ*cf21;
    p[8] = f20*m02 + f21*m12 + f22*m22 + aJ*cf22;
}

extern "C" void kernel_launch(void* const* d_in, const int* in_sizes, int n_in,
                              void* d_out, int out_size, void* d_ws, size_t ws_size,
                              hipStream_t stream) {
    const float* F  = (const float*)d_in[0];
    const float* W0 = (const float*)d_in[1];
    const float* b0 = (const float*)d_in[2];
    const float* W1 = (const float*)d_in[3];
    const float* b1 = (const float*)d_in[4];
    const float* W2 = (const float*)d_in[5];
    const float* b2 = (const float*)d_in[6];
    int n = in_sizes[0] / 9;
    float* out = (float*)d_out;
    float* P  = out;                       // [n,3,3] flat
    float* Wv = out + (size_t)n * 9;       // [n,1] flat

    int block = 256;
    int grid = (n + block - 1) / block;
    hipLaunchKernelGGL(energy_kernel, dim3(grid), dim3(block), 0, stream,
                       F, W0, b0, W1, b1, W2, b2, P, Wv, n);
}